// Round 17
// baseline (404.713 us; speedup 1.0000x reference)
//
#include <hip/hip_runtime.h>
#include <stdint.h>

typedef short s16x8 __attribute__((ext_vector_type(8)));
typedef short s16x4 __attribute__((ext_vector_type(4)));
typedef float f32x4 __attribute__((ext_vector_type(4)));

__device__ __forceinline__ unsigned short f2bf(float f) {
  union { float f; unsigned int u; } v; v.f = f;
  unsigned int r = v.u + 0x7FFFu + ((v.u >> 16) & 1u);
  return (unsigned short)(r >> 16);
}

// HW packed f32x2 -> e4m3x2 (low word: byte0=cvt(a), byte1=cvt(b))
__device__ __forceinline__ unsigned cvt2fp8(float a, float b) {
#if __has_builtin(__builtin_amdgcn_cvt_pk_fp8_f32)
  return (unsigned)__builtin_amdgcn_cvt_pk_fp8_f32(a, b, 0, false);
#else
  unsigned r;
  asm("v_cvt_pk_fp8_f32 %0, %1, %2" : "=v"(r) : "v"(a), "v"(b));
  return r;
#endif
}

__device__ __forceinline__ void gload_lds16(const void* g, void* l) {
  __builtin_amdgcn_global_load_lds(
      (const __attribute__((address_space(1))) unsigned int*)g,
      (__attribute__((address_space(3))) unsigned int*)l, 16, 0, 0);
}

// T1 XCD-aware bijective block swizzle (grid size must be %8==0; all ours are).
__device__ __forceinline__ unsigned xcd_swz(unsigned fid, unsigned nwg) {
  unsigned cpx = nwg >> 3;
  return (fid & 7) * cpx + (fid >> 3);
}

// ---------------- converts ----------------
// f32 -> fp8 e4m3 via HW cvt (values ~N(0,1) or bounded << 448)
__global__ void conv_fp8(const float* __restrict__ in, unsigned char* __restrict__ out, int n8) {
  int i = blockIdx.x * blockDim.x + threadIdx.x;
  if (i >= n8) return;
  const f32x4* p = (const f32x4*)(in + (long)i * 8);
  f32x4 a = p[0], b = p[1];
  unsigned long w = (unsigned long)(cvt2fp8(a[0], a[1]) & 0xFFFFu)
                  | ((unsigned long)(cvt2fp8(a[2], a[3]) & 0xFFFFu) << 16)
                  | ((unsigned long)(cvt2fp8(b[0], b[1]) & 0xFFFFu) << 32)
                  | ((unsigned long)(cvt2fp8(b[2], b[3]) & 0xFFFFu) << 48);
  *(unsigned long*)(out + (long)i * 8) = w;
}

// Wv: [16][1024][64] f32 -> WvT [16][64][1024] fp8
__global__ void convT_wv_f8(const float* __restrict__ in, unsigned char* __restrict__ out) {
  int i = blockIdx.x * blockDim.x + threadIdx.x; // 1M
  int v = i & 63, d = (i >> 6) & 1023, h = i >> 16;
  out[((long)h * 64 + v) * 1024 + d] = (unsigned char)cvt2fp8(in[i], 0.f);
}

// Wo: [1024][1024] f32 [c][e] -> WoT [e][c] bf16
__global__ void convT_wo(const float* __restrict__ in, unsigned short* __restrict__ out) {
  int i = blockIdx.x * blockDim.x + threadIdx.x; // 1M
  int e = i & 1023, c = i >> 10;
  out[(long)e * 1024 + c] = f2bf(in[i]);
}

// ---------------- bf16 bt-GEMM (Y only), K=1024 fixed ----------------
// CMODE 2: f32 masked (col>row -> -1e9); fully-masked tiles skip the K-loop.
template<int BM, int BN, int WAVES_M, int WAVES_N, int CMODE>
__global__ __launch_bounds__(256, 2)
void gemm_bt(const unsigned short* __restrict__ A, const unsigned short* __restrict__ BT,
             void* __restrict__ Cout, int aDiv, long aStr, int bMod, long bStr,
             long cStr, int ldc)
{
  constexpr int BK = 64;
  constexpr int FM = BM / (WAVES_M * 16);
  constexpr int FN = BN / (WAVES_N * 16);
  __shared__ __align__(16) unsigned short At[BM * BK];
  __shared__ __align__(16) unsigned short Bt[BN * BK];

  unsigned fid = blockIdx.x + gridDim.x * (blockIdx.y + gridDim.y * blockIdx.z);
  unsigned nwg = gridDim.x * gridDim.y * gridDim.z;
  unsigned sid = xcd_swz(fid, nwg);
  unsigned bx = sid % gridDim.x;
  unsigned rem = sid / gridDim.x;
  unsigned by = rem % gridDim.y;
  unsigned bz = rem / gridDim.y;

  const int t = threadIdx.x;
  const int l = t & 63;
  const int g = l >> 4, c = l & 15;
  const int w = t >> 6;
  const int wr = (w / WAVES_N) * (BM / WAVES_M);
  const int wc = (w % WAVES_N) * (BN / WAVES_N);
  const int z = bz;
  const int m0 = by * BM;
  const int n0 = bx * BN;
  const unsigned short* Ab = A + (long)(z / aDiv) * aStr + (long)m0 * 1024;
  const unsigned short* Bb = BT + (long)(z % bMod) * bStr + (long)n0 * 1024;

  const long cbase = (long)z * cStr;

  if constexpr (CMODE == 2) {
    if (n0 > m0 + BM - 1) {
#pragma unroll
      for (int m = 0; m < FM; ++m)
#pragma unroll
        for (int n = 0; n < FN; ++n)
#pragma unroll
          for (int r = 0; r < 4; ++r) {
            int row = wr + m * 16 + g * 4 + r;
            int col = n0 + wc + n * 16 + c;
            ((float*)Cout)[cbase + (long)(m0 + row) * ldc + col] = -1e9f;
          }
      return;
    }
  }

  f32x4 acc[FM][FN] = {};
  constexpr int PA = (BM * BK) / 2048;
  constexpr int PB = (BN * BK) / 2048;

  for (int k0 = 0; k0 < 1024; k0 += BK) {
#pragma unroll
    for (int p = 0; p < PA; ++p) {
      int e = (p * 256 + t) * 8;
      int row = e >> 6, col = e & 63;
      gload_lds16(Ab + (long)row * 1024 + k0 + col, &At[e]);
    }
#pragma unroll
    for (int p = 0; p < PB; ++p) {
      int e = (p * 256 + t) * 8;
      int row = e >> 6, col = e & 63;
      gload_lds16(Bb + (long)row * 1024 + k0 + col, &Bt[e]);
    }
    __syncthreads();
#pragma unroll
    for (int kk = 0; kk < BK; kk += 32) {
      s16x8 af[FM], bf[FN];
#pragma unroll
      for (int m = 0; m < FM; ++m)
        af[m] = *(const s16x8*)&At[(wr + m * 16 + c) * BK + kk + g * 8];
#pragma unroll
      for (int n = 0; n < FN; ++n)
        bf[n] = *(const s16x8*)&Bt[(wc + n * 16 + c) * BK + kk + g * 8];
#pragma unroll
      for (int m = 0; m < FM; ++m)
#pragma unroll
        for (int n = 0; n < FN; ++n)
          acc[m][n] = __builtin_amdgcn_mfma_f32_16x16x32_bf16(af[m], bf[n], acc[m][n], 0, 0, 0);
    }
    __syncthreads();
  }

#pragma unroll
  for (int m = 0; m < FM; ++m)
#pragma unroll
    for (int n = 0; n < FN; ++n)
#pragma unroll
      for (int r = 0; r < 4; ++r) {
        int row = wr + m * 16 + g * 4 + r;
        int col = n0 + wc + n * 16 + c;
        int grow = m0 + row;
        float v = acc[m][n][r];
        if constexpr (CMODE == 0) {
          ((unsigned short*)Cout)[cbase + (long)grow * ldc + col] = f2bf(v);
        } else if constexpr (CMODE == 2) {
          ((float*)Cout)[cbase + (long)grow * ldc + col] = (col > grow) ? -1e9f : v;
        }
      }
}

// ---------------- generalized fp8 bt-GEMM (BK=128, r12-validated structure) -
// C[i][j] = scale * sum_k A[i][k]*BT[j][k]; A,BT e4m3 with 1024B rows.
// TRANS 0: fp8 out at [row*ldc+col]; TRANS 1: fp8 out transposed (u32 packs).
// cStr/aStr/bStr/ldc in BYTES.  128B LDS rows + 16B-unit XOR unit^(row&7);
// staged tiles keep LDS linear + inverse-swizzled GLOBAL source (rule #21).
// [r16 lesson: MX K=128 MFMA spills at this fragment fan-out — stay K=32.]
template<int BM, int BN, int WM, int WN, int TRANS>
__global__ __launch_bounds__(256, 2)
void gemm_f8(const unsigned char* __restrict__ A, const unsigned char* __restrict__ BT,
             unsigned char* __restrict__ Cout, int aDiv, long aStr, int bMod, long bStr,
             long cStr, int ldc, float scale)
{
  constexpr int FM = BM / (WM * 16);
  constexpr int FN = BN / (WN * 16);
  __shared__ __align__(16) unsigned char At[BM * 128];
  __shared__ __align__(16) unsigned char Bt[BN * 128];

  unsigned fid = blockIdx.x + gridDim.x * (blockIdx.y + gridDim.y * blockIdx.z);
  unsigned nwg = gridDim.x * gridDim.y * gridDim.z;
  unsigned sid = xcd_swz(fid, nwg);
  unsigned bx = sid % gridDim.x;
  unsigned rem = sid / gridDim.x;
  unsigned by = rem % gridDim.y;
  unsigned bz = rem / gridDim.y;

  const int t = threadIdx.x;
  const int l = t & 63;
  const int g = l >> 4, c = l & 15;
  const int w = t >> 6;
  const int wr = (w / WN) * (BM / WM);
  const int wc = (w % WN) * (BN / WN);
  const int z = bz;
  const int m0 = by * BM;
  const int n0 = bx * BN;
  const unsigned char* Ab = A + (long)(z / aDiv) * aStr + (long)m0 * 1024;
  const unsigned char* Bb = BT + (long)(z % bMod) * bStr + (long)n0 * 1024;

  f32x4 acc[FM][FN] = {};
  constexpr int PA = (BM * 128) / (256 * 16);
  constexpr int PB = (BN * 128) / (256 * 16);

  for (int k0 = 0; k0 < 1024; k0 += 128) {
#pragma unroll
    for (int p = 0; p < PA; ++p) {
      int e = (p * 256 + t) * 16;
      int r = e >> 7, u = (e >> 4) & 7;
      int gcol = ((u ^ (r & 7)) << 4);
      gload_lds16(Ab + (long)r * 1024 + k0 + gcol, &At[e]);
    }
#pragma unroll
    for (int p = 0; p < PB; ++p) {
      int e = (p * 256 + t) * 16;
      int r = e >> 7, u = (e >> 4) & 7;
      int gcol = ((u ^ (r & 7)) << 4);
      gload_lds16(Bb + (long)r * 1024 + k0 + gcol, &Bt[e]);
    }
    __syncthreads();
#pragma unroll
    for (int kk = 0; kk < 128; kk += 32) {
      long af[FM], bf[FN];
#pragma unroll
      for (int m = 0; m < FM; ++m) {
        int row = wr + m * 16 + c;
        int un = (kk >> 4) + (g >> 1);
        af[m] = *(const long*)&At[row * 128 + ((un ^ (row & 7)) << 4) + (g & 1) * 8];
      }
#pragma unroll
      for (int n = 0; n < FN; ++n) {
        int row = wc + n * 16 + c;
        int un = (kk >> 4) + (g >> 1);
        bf[n] = *(const long*)&Bt[row * 128 + ((un ^ (row & 7)) << 4) + (g & 1) * 8];
      }
      __builtin_amdgcn_s_setprio(1);
#pragma unroll
      for (int m = 0; m < FM; ++m)
#pragma unroll
        for (int n = 0; n < FN; ++n)
          acc[m][n] = __builtin_amdgcn_mfma_f32_16x16x32_fp8_fp8(af[m], bf[n], acc[m][n], 0, 0, 0);
      __builtin_amdgcn_s_setprio(0);
    }
    __syncthreads();
  }

  const long cbase = (long)z * cStr;
#pragma unroll
  for (int m = 0; m < FM; ++m)
#pragma unroll
    for (int n = 0; n < FN; ++n) {
      int row0 = m0 + wr + m * 16 + g * 4;
      int col  = n0 + wc + n * 16 + c;
      unsigned p01 = cvt2fp8(acc[m][n][0] * scale, acc[m][n][1] * scale);
      unsigned p23 = cvt2fp8(acc[m][n][2] * scale, acc[m][n][3] * scale);
      if constexpr (TRANS == 0) {
        unsigned char* Cp = Cout + cbase + (long)row0 * ldc + col;
        Cp[0]            = (unsigned char)p01;
        Cp[(long)ldc]    = (unsigned char)(p01 >> 8);
        Cp[(long)ldc*2]  = (unsigned char)p23;
        Cp[(long)ldc*3]  = (unsigned char)(p23 >> 8);
      } else {
        unsigned word = (p01 & 0xFFFFu) | (p23 << 16);
        *(unsigned*)(Cout + cbase + (long)col * ldc + row0) = word;
      }
    }
}

// ---------------- flash attention (fp8, split-KV: 2 blocks per (q0,bh)) ----
// Round-17: grid 512->1024 blocks (split s covers keys [512s, 512s+512)) ->
// 4 blocks/CU (LDS 4x40KB = 160KB exactly), doubling TLP WITHOUT diluting
// per-wave tile efficiency (r6/r11's failure mode).  Epilogue writes
// unnormalized fp32 O + per-row (m,l); flash_merge combines the 2 partials.
// Body = r15-validated structure (queries X[b] L2-hot, keys R read once).
// LDS (40 KB): Qt[128][128]fp8 | Kt[128][128]fp8 | Vt8[64][128]fp8;
// Pl8 aliases Qt.  128B rows, 16B-unit XOR unit^(row&7).
// bounds(256,4): VGPR cap 128 (r15 used 112; epilogue is simpler -> safe).
__global__ __launch_bounds__(256, 4)
void flash_attn(const unsigned char* __restrict__ R, const unsigned char* __restrict__ X,
                const unsigned char* __restrict__ VT,
                float* __restrict__ Opart, float* __restrict__ ML)
{
  __shared__ __align__(16) unsigned char Sh[40960]; // 40 KB
  unsigned char* Qt  = Sh;             // [128][128] fp8 (queries = X rows)
  unsigned char* Kt  = Sh + 16384;     // [128][128] fp8 (keys = R rows)
  unsigned char* Vt8 = Sh + 32768;     // [64][128] fp8
  unsigned char* Pl8 = Sh;             // [128][128] fp8, aliases Qt

  unsigned fid = blockIdx.x + gridDim.x * blockIdx.y;
  unsigned nwg = gridDim.x * gridDim.y;          // 1024
  unsigned sid = xcd_swz(fid, nwg);
  const int q0    = (sid % gridDim.x) * 128;
  const int rest  = sid / gridDim.x;             // 0..127
  const int bh    = rest >> 1;
  const int split = rest & 1;

  const int t = threadIdx.x;
  const int l = t & 63;
  const int w = t >> 6;
  const int g = l >> 4;
  const int c = l & 15;
  const int b = bh >> 4;

  const unsigned char* Qq = X + (long)b * (1024 * 1024) + (long)q0 * 1024; // queries
  const unsigned char* Kb = R + (long)bh * (1024 * 1024);                  // keys
  const unsigned char* Vb = VT + (long)bh * (64 * 1024);

  f32x4 accO[2][4] = {};
  float mrun[2][4], lrun[2][4];
#pragma unroll
  for (int m = 0; m < 2; ++m)
#pragma unroll
    for (int r = 0; r < 4; ++r) { mrun[m][r] = -1e30f; lrun[m][r] = 0.f; }

  const float scale = 8.0f; // (1/32 score scale) * 256 (R prescale)

  const int mlo = split * 512, mhi = mlo + 512;
  for (int m0 = mlo; m0 < mhi; m0 += 128) {
    // ---- S = Q(128xK) * Keys(128xK)^T, K=1024 tiled by 128 (fp8)
    f32x4 accS[2][8] = {};
    for (int k0 = 0; k0 < 1024; k0 += 128) {
#pragma unroll
      for (int p = 0; p < 4; ++p) {
        int e = (p * 256 + t) * 16;
        int r = e >> 7, u = (e >> 4) & 7;
        int gcol = ((u ^ (r & 7)) << 4);
        gload_lds16(Qq + (long)r * 1024 + k0 + gcol, &Qt[e]);
      }
#pragma unroll
      for (int p = 0; p < 4; ++p) {
        int e = (p * 256 + t) * 16;
        int r = e >> 7, u = (e >> 4) & 7;
        int gcol = ((u ^ (r & 7)) << 4);
        gload_lds16(Kb + (long)(m0 + r) * 1024 + k0 + gcol, &Kt[e]);
      }
      __syncthreads();
#pragma unroll
      for (int kk = 0; kk < 128; kk += 32) {
        long af[2], bf[8];
#pragma unroll
        for (int m = 0; m < 2; ++m) {
          int row = w * 32 + m * 16 + c;
          int un = (kk >> 4) + (g >> 1);
          af[m] = *(const long*)&Qt[row * 128 + ((un ^ (row & 7)) << 4) + (g & 1) * 8];
        }
#pragma unroll
        for (int n = 0; n < 8; ++n) {
          int row = n * 16 + c;
          int un = (kk >> 4) + (g >> 1);
          bf[n] = *(const long*)&Kt[row * 128 + ((un ^ (row & 7)) << 4) + (g & 1) * 8];
        }
        __builtin_amdgcn_s_setprio(1);
#pragma unroll
        for (int m = 0; m < 2; ++m)
#pragma unroll
          for (int n = 0; n < 8; ++n)
            accS[m][n] = __builtin_amdgcn_mfma_f32_16x16x32_fp8_fp8(af[m], bf[n], accS[m][n], 0, 0, 0);
        __builtin_amdgcn_s_setprio(0);
      }
      __syncthreads();
    }
    // stage V slab [64][128] fp8 (flies under softmax; drained at syncthreads)
#pragma unroll
    for (int p = 0; p < 2; ++p) {
      int e = (p * 256 + t) * 16;
      int r = e >> 7, u = (e >> 4) & 7;
      int gcol = ((u ^ (r & 7)) << 4);
      gload_lds16(Vb + (long)r * 1024 + m0 + gcol, &Vt8[e]);
    }
    // ---- online softmax update (rows spread over 16-lane groups)
    float alpha[2][4];
#pragma unroll
    for (int m = 0; m < 2; ++m) {
#pragma unroll
      for (int r = 0; r < 4; ++r) {
        float mx = -1e30f;
#pragma unroll
        for (int n = 0; n < 8; ++n) mx = fmaxf(mx, accS[m][n][r]);
#pragma unroll
        for (int s = 1; s < 16; s <<= 1) mx = fmaxf(mx, __shfl_xor(mx, s));
        mx *= scale;
        float mnew = fmaxf(mrun[m][r], mx);
        float a = __expf(mrun[m][r] - mnew);
        alpha[m][r] = a;
        float sum = 0.f;
#pragma unroll
        for (int n = 0; n < 8; ++n) {
          float pe = __expf(accS[m][n][r] * scale - mnew);
          accS[m][n][r] = pe;
          sum += pe;
        }
#pragma unroll
        for (int s = 1; s < 16; s <<= 1) sum += __shfl_xor(sum, s);
        lrun[m][r] = lrun[m][r] * a + sum;
        mrun[m][r] = mnew;
      }
    }
    // P -> LDS (fp8, swizzled), aliases Qt (safe: last k0 barrier passed)
#pragma unroll
    for (int m = 0; m < 2; ++m)
#pragma unroll
      for (int n = 0; n < 8; ++n)
#pragma unroll
        for (int r = 0; r < 4; ++r) {
          int row = w * 32 + m * 16 + g * 4 + r;
          Pl8[row * 128 + ((n ^ (row & 7)) << 4) + c] =
              (unsigned char)cvt2fp8(accS[m][n][r], 0.f);
        }
    __syncthreads();   // Pl8 visible + Vt8 staged (vmcnt drained by barrier)
    // ---- O = O*alpha + P(32x128) @ V(128x64)   (fp8 MFMA)
#pragma unroll
    for (int m = 0; m < 2; ++m)
#pragma unroll
      for (int n = 0; n < 4; ++n)
#pragma unroll
        for (int r = 0; r < 4; ++r)
          accO[m][n][r] *= alpha[m][r];
#pragma unroll
    for (int kk = 0; kk < 128; kk += 32) {
      long pa[2], vb[4];
#pragma unroll
      for (int m = 0; m < 2; ++m) {
        int row = w * 32 + m * 16 + c;
        int un = (kk >> 4) + (g >> 1);
        pa[m] = *(const long*)&Pl8[row * 128 + ((un ^ (row & 7)) << 4) + (g & 1) * 8];
      }
#pragma unroll
      for (int n = 0; n < 4; ++n) {
        int row = n * 16 + c;
        int un = (kk >> 4) + (g >> 1);
        vb[n] = *(const long*)&Vt8[row * 128 + ((un ^ (row & 7)) << 4) + (g & 1) * 8];
      }
      __builtin_amdgcn_s_setprio(1);
#pragma unroll
      for (int m = 0; m < 2; ++m)
#pragma unroll
        for (int n = 0; n < 4; ++n)
          accO[m][n] = __builtin_amdgcn_mfma_f32_16x16x32_fp8_fp8(pa[m], vb[n], accO[m][n], 0, 0, 0);
      __builtin_amdgcn_s_setprio(0);
    }
    __syncthreads();   // all done reading Pl8/Vt8 before next m0 restage
  }
  // epilogue: write unnormalized O (f32) + per-row (m, l) partials
  const int part = (bh << 1) + split;
  float* Op = Opart + (long)part * 65536;        // [1024][64] f32
#pragma unroll
  for (int m = 0; m < 2; ++m)
#pragma unroll
    for (int n = 0; n < 4; ++n)
#pragma unroll
      for (int r = 0; r < 4; ++r) {
        int row = q0 + w * 32 + m * 16 + g * 4 + r;
        int col = n * 16 + c;
        Op[(long)row * 64 + col] = accO[m][n][r];
      }
  if (c == 0) {
#pragma unroll
    for (int m = 0; m < 2; ++m)
#pragma unroll
      for (int r = 0; r < 4; ++r) {
        int row = q0 + w * 32 + m * 16 + g * 4 + r;
        ML[(long)part * 2048 + row * 2]     = mrun[m][r];
        ML[(long)part * 2048 + row * 2 + 1] = lrun[m][r];
      }
  }
}

// ---------------- split-KV merge: combine 2 partials -> concat bf16 --------
// 1M threads, 4 v-elements each.  O = (O0*a0 + O1*a1) / (l0*a0 + l1*a1).
__global__ void flash_merge(const float* __restrict__ Opart, const float* __restrict__ ML,
                            unsigned short* __restrict__ Yc)
{
  int i = blockIdx.x * blockDim.x + threadIdx.x;  // 0 .. 1M
  int bh  = i >> 14;
  int rem = i & 16383;
  int row = rem >> 4;
  int v4  = (rem & 15) * 4;
  int p0 = bh << 1;
  float m0 = ML[(long)p0 * 2048 + row * 2];
  float l0 = ML[(long)p0 * 2048 + row * 2 + 1];
  float m1 = ML[(long)(p0 + 1) * 2048 + row * 2];
  float l1 = ML[(long)(p0 + 1) * 2048 + row * 2 + 1];
  float mn = fmaxf(m0, m1);
  float a0 = __expf(m0 - mn), a1 = __expf(m1 - mn);
  float inv = 1.f / (l0 * a0 + l1 * a1);
  f32x4 o0 = *(const f32x4*)&Opart[(long)p0 * 65536 + (long)row * 64 + v4];
  f32x4 o1 = *(const f32x4*)&Opart[(long)(p0 + 1) * 65536 + (long)row * 64 + v4];
  int b = bh >> 4, h = bh & 15;
  s16x4 o;
  o[0] = (short)f2bf((o0[0] * a0 + o1[0] * a1) * inv);
  o[1] = (short)f2bf((o0[1] * a0 + o1[1] * a1) * inv);
  o[2] = (short)f2bf((o0[2] * a0 + o1[2] * a1) * inv);
  o[3] = (short)f2bf((o0[3] * a0 + o1[3] * a1) * inv);
  *(s16x4*)(Yc + (long)b * (1024 * 1024) + (long)row * 1024 + h * 64 + v4) = o;
}

// ---------------- launch ----------------
extern "C" void kernel_launch(void* const* d_in, const int* in_sizes, int n_in,
                              void* d_out, int out_size, void* d_ws, size_t ws_size,
                              hipStream_t stream) {
  (void)in_sizes; (void)n_in; (void)out_size; (void)ws_size;
  const float* X  = (const float*)d_in[0];
  const float* Wq = (const float*)d_in[1];
  const float* Wk = (const float*)d_in[2];
  const float* Wv = (const float*)d_in[3];
  const float* Wo = (const float*)d_in[4];
  float* Y = (float*)d_out;
  char* ws = (char*)d_ws;

  const long MB = 1L << 20;
  unsigned char*  Xf8   = (unsigned char*)(ws + 0);         // 4 MB
  unsigned char*  Wqf8  = (unsigned char*)(ws + 4  * MB);   // 16 MB
  unsigned char*  Wkf8  = (unsigned char*)(ws + 20 * MB);   // 16 MB
  unsigned char*  Mf8   = (unsigned char*)(ws + 36 * MB);   // 16 MB  (M = Wq·Wk^T, /256)
  unsigned char*  WvTf8 = (unsigned char*)(ws + 52 * MB);   // 1 MB
  unsigned char*  VTb8  = (unsigned char*)(ws + 56 * MB);   // 4 MB
  unsigned short* Ccat  = (unsigned short*)(ws + 60 * MB);  // 8 MB
  unsigned short* WoT   = (unsigned short*)(ws + 68 * MB);  // 2 MB
  unsigned char*  Rf8   = (unsigned char*)(ws + 72 * MB);   // 64 MB
  float*          Opart = (float*)(ws + 136 * MB);          // 32 MB
  float*          MLb   = (float*)(ws + 168 * MB);          // 1 MB -> 169 MB peak

  const long M1 = 1L << 20; // byte stride for [1024][1024] fp8

  // converts (all inputs -> fp8; Wo -> bf16 transposed)
  conv_fp8<<<2048, 256, 0, stream>>>(X,  Xf8,  524288);
  conv_fp8<<<8192, 256, 0, stream>>>(Wq, Wqf8, 2097152);
  conv_fp8<<<8192, 256, 0, stream>>>(Wk, Wkf8, 2097152);
  convT_wv_f8<<<4096, 256, 0, stream>>>(Wv, WvTf8);

  // Mf8[h] = (Wq[h] @ Wk[h]^T)/256 in e4m3   (bt-form: A=Wq, BT=Wk)
  gemm_f8<128, 128, 2, 2, 0><<<dim3(8, 8, 16), 256, 0, stream>>>(
      Wqf8, Wkf8, Mf8, 1, M1, 16, M1, M1, 1024, 0.00390625f);

  // Rf8[b,h] = X[b] @ (M[h]^T/256) in e4m3   (bt-form: A=X, BT=Mf8)
  gemm_f8<128, 128, 2, 2, 0><<<dim3(8, 8, 64), 256, 0, stream>>>(
      Xf8, Mf8, Rf8, 16, M1, 16, M1, M1, 1024, 1.0f);

  // VTb8[b,h][64][1024] = (X[b] @ Wv[h]) transposed, e4m3
  gemm_f8<128, 64, 4, 1, 1><<<dim3(1, 8, 64), 256, 0, stream>>>(
      Xf8, WvTf8, VTb8, 16, M1, 16, 65536, 65536, 1024, 1.0f);

  // flash attention, split-KV (2 partials per (q0,bh)) + merge -> concat bf16
  flash_attn<<<dim3(8, 128), 256, 0, stream>>>(Rf8, Xf8, VTb8, Opart, MLb);
  flash_merge<<<4096, 256, 0, stream>>>(Opart, MLb, Ccat);

  // Y = concat @ Wo, masked epilogue (col > row -> -1e9), fp32 out;
  // fully-masked tiles (n0 > m0+127) skip their K-loop.
  convT_wo<<<4096, 256, 0, stream>>>(Wo, WoT);
  gemm_bt<128, 128, 2, 2, 2><<<dim3(8, 8, 4), 256, 0, stream>>>(
      Ccat, WoT, Y, 1, M1, 1, 0, M1, 1024);
}

// Round 18
// 347.952 us; speedup vs baseline: 1.1631x; 1.1631x over previous
//
#include <hip/hip_runtime.h>
#include <stdint.h>

typedef short s16x8 __attribute__((ext_vector_type(8)));
typedef short s16x4 __attribute__((ext_vector_type(4)));
typedef float f32x4 __attribute__((ext_vector_type(4)));

__device__ __forceinline__ unsigned short f2bf(float f) {
  union { float f; unsigned int u; } v; v.f = f;
  unsigned int r = v.u + 0x7FFFu + ((v.u >> 16) & 1u);
  return (unsigned short)(r >> 16);
}

// HW packed f32x2 -> e4m3x2 (low word: byte0=cvt(a), byte1=cvt(b))
__device__ __forceinline__ unsigned cvt2fp8(float a, float b) {
#if __has_builtin(__builtin_amdgcn_cvt_pk_fp8_f32)
  return (unsigned)__builtin_amdgcn_cvt_pk_fp8_f32(a, b, 0, false);
#else
  unsigned r;
  asm("v_cvt_pk_fp8_f32 %0, %1, %2" : "=v"(r) : "v"(a), "v"(b));
  return r;
#endif
}

__device__ __forceinline__ void gload_lds16(const void* g, void* l) {
  __builtin_amdgcn_global_load_lds(
      (const __attribute__((address_space(1))) unsigned int*)g,
      (__attribute__((address_space(3))) unsigned int*)l, 16, 0, 0);
}

// T1 XCD-aware bijective block swizzle (grid size must be %8==0; all ours are).
__device__ __forceinline__ unsigned xcd_swz(unsigned fid, unsigned nwg) {
  unsigned cpx = nwg >> 3;
  return (fid & 7) * cpx + (fid >> 3);
}

// ---------------- converts ----------------
// f32 -> fp8 e4m3 via HW cvt (values ~N(0,1) or bounded << 448)
__global__ void conv_fp8(const float* __restrict__ in, unsigned char* __restrict__ out, int n8) {
  int i = blockIdx.x * blockDim.x + threadIdx.x;
  if (i >= n8) return;
  const f32x4* p = (const f32x4*)(in + (long)i * 8);
  f32x4 a = p[0], b = p[1];
  unsigned long w = (unsigned long)(cvt2fp8(a[0], a[1]) & 0xFFFFu)
                  | ((unsigned long)(cvt2fp8(a[2], a[3]) & 0xFFFFu) << 16)
                  | ((unsigned long)(cvt2fp8(b[0], b[1]) & 0xFFFFu) << 32)
                  | ((unsigned long)(cvt2fp8(b[2], b[3]) & 0xFFFFu) << 48);
  *(unsigned long*)(out + (long)i * 8) = w;
}

// Wv: [16][1024][64] f32 -> WvT [16][64][1024] fp8
__global__ void convT_wv_f8(const float* __restrict__ in, unsigned char* __restrict__ out) {
  int i = blockIdx.x * blockDim.x + threadIdx.x; // 1M
  int v = i & 63, d = (i >> 6) & 1023, h = i >> 16;
  out[((long)h * 64 + v) * 1024 + d] = (unsigned char)cvt2fp8(in[i], 0.f);
}

// Wo: [1024][1024] f32 [c][e] -> WoT [e][c] bf16
__global__ void convT_wo(const float* __restrict__ in, unsigned short* __restrict__ out) {
  int i = blockIdx.x * blockDim.x + threadIdx.x; // 1M
  int e = i & 1023, c = i >> 10;
  out[(long)e * 1024 + c] = f2bf(in[i]);
}

// ---------------- bf16 bt-GEMM (Y only), K=1024 fixed ----------------
// CMODE 2: f32 masked (col>row -> -1e9); fully-masked tiles skip the K-loop.
template<int BM, int BN, int WAVES_M, int WAVES_N, int CMODE>
__global__ __launch_bounds__(256, 2)
void gemm_bt(const unsigned short* __restrict__ A, const unsigned short* __restrict__ BT,
             void* __restrict__ Cout, int aDiv, long aStr, int bMod, long bStr,
             long cStr, int ldc)
{
  constexpr int BK = 64;
  constexpr int FM = BM / (WAVES_M * 16);
  constexpr int FN = BN / (WAVES_N * 16);
  __shared__ __align__(16) unsigned short At[BM * BK];
  __shared__ __align__(16) unsigned short Bt[BN * BK];

  unsigned fid = blockIdx.x + gridDim.x * (blockIdx.y + gridDim.y * blockIdx.z);
  unsigned nwg = gridDim.x * gridDim.y * gridDim.z;
  unsigned sid = xcd_swz(fid, nwg);
  unsigned bx = sid % gridDim.x;
  unsigned rem = sid / gridDim.x;
  unsigned by = rem % gridDim.y;
  unsigned bz = rem / gridDim.y;

  const int t = threadIdx.x;
  const int l = t & 63;
  const int g = l >> 4, c = l & 15;
  const int w = t >> 6;
  const int wr = (w / WAVES_N) * (BM / WAVES_M);
  const int wc = (w % WAVES_N) * (BN / WAVES_N);
  const int z = bz;
  const int m0 = by * BM;
  const int n0 = bx * BN;
  const unsigned short* Ab = A + (long)(z / aDiv) * aStr + (long)m0 * 1024;
  const unsigned short* Bb = BT + (long)(z % bMod) * bStr + (long)n0 * 1024;

  const long cbase = (long)z * cStr;

  if constexpr (CMODE == 2) {
    if (n0 > m0 + BM - 1) {
#pragma unroll
      for (int m = 0; m < FM; ++m)
#pragma unroll
        for (int n = 0; n < FN; ++n)
#pragma unroll
          for (int r = 0; r < 4; ++r) {
            int row = wr + m * 16 + g * 4 + r;
            int col = n0 + wc + n * 16 + c;
            ((float*)Cout)[cbase + (long)(m0 + row) * ldc + col] = -1e9f;
          }
      return;
    }
  }

  f32x4 acc[FM][FN] = {};
  constexpr int PA = (BM * BK) / 2048;
  constexpr int PB = (BN * BK) / 2048;

  for (int k0 = 0; k0 < 1024; k0 += BK) {
#pragma unroll
    for (int p = 0; p < PA; ++p) {
      int e = (p * 256 + t) * 8;
      int row = e >> 6, col = e & 63;
      gload_lds16(Ab + (long)row * 1024 + k0 + col, &At[e]);
    }
#pragma unroll
    for (int p = 0; p < PB; ++p) {
      int e = (p * 256 + t) * 8;
      int row = e >> 6, col = e & 63;
      gload_lds16(Bb + (long)row * 1024 + k0 + col, &Bt[e]);
    }
    __syncthreads();
#pragma unroll
    for (int kk = 0; kk < BK; kk += 32) {
      s16x8 af[FM], bf[FN];
#pragma unroll
      for (int m = 0; m < FM; ++m)
        af[m] = *(const s16x8*)&At[(wr + m * 16 + c) * BK + kk + g * 8];
#pragma unroll
      for (int n = 0; n < FN; ++n)
        bf[n] = *(const s16x8*)&Bt[(wc + n * 16 + c) * BK + kk + g * 8];
#pragma unroll
      for (int m = 0; m < FM; ++m)
#pragma unroll
        for (int n = 0; n < FN; ++n)
          acc[m][n] = __builtin_amdgcn_mfma_f32_16x16x32_bf16(af[m], bf[n], acc[m][n], 0, 0, 0);
    }
    __syncthreads();
  }

#pragma unroll
  for (int m = 0; m < FM; ++m)
#pragma unroll
    for (int n = 0; n < FN; ++n)
#pragma unroll
      for (int r = 0; r < 4; ++r) {
        int row = wr + m * 16 + g * 4 + r;
        int col = n0 + wc + n * 16 + c;
        int grow = m0 + row;
        float v = acc[m][n][r];
        if constexpr (CMODE == 0) {
          ((unsigned short*)Cout)[cbase + (long)grow * ldc + col] = f2bf(v);
        } else if constexpr (CMODE == 2) {
          ((float*)Cout)[cbase + (long)grow * ldc + col] = (col > grow) ? -1e9f : v;
        }
      }
}

// ---------------- generalized fp8 bt-GEMM (BK=128, r12-validated structure) -
// C[i][j] = scale * sum_k A[i][k]*BT[j][k]; A,BT e4m3 with 1024B rows.
// TRANS 0: fp8 out at [row*ldc+col]; TRANS 1: fp8 out transposed (u32 packs).
// cStr/aStr/bStr/ldc in BYTES.  128B LDS rows + 16B-unit XOR unit^(row&7);
// staged tiles keep LDS linear + inverse-swizzled GLOBAL source (rule #21).
// [r16 lesson: MX K=128 MFMA spills at this fragment fan-out — stay K=32.]
template<int BM, int BN, int WM, int WN, int TRANS>
__global__ __launch_bounds__(256, 2)
void gemm_f8(const unsigned char* __restrict__ A, const unsigned char* __restrict__ BT,
             unsigned char* __restrict__ Cout, int aDiv, long aStr, int bMod, long bStr,
             long cStr, int ldc, float scale)
{
  constexpr int FM = BM / (WM * 16);
  constexpr int FN = BN / (WN * 16);
  __shared__ __align__(16) unsigned char At[BM * 128];
  __shared__ __align__(16) unsigned char Bt[BN * 128];

  unsigned fid = blockIdx.x + gridDim.x * (blockIdx.y + gridDim.y * blockIdx.z);
  unsigned nwg = gridDim.x * gridDim.y * gridDim.z;
  unsigned sid = xcd_swz(fid, nwg);
  unsigned bx = sid % gridDim.x;
  unsigned rem = sid / gridDim.x;
  unsigned by = rem % gridDim.y;
  unsigned bz = rem / gridDim.y;

  const int t = threadIdx.x;
  const int l = t & 63;
  const int g = l >> 4, c = l & 15;
  const int w = t >> 6;
  const int wr = (w / WN) * (BM / WM);
  const int wc = (w % WN) * (BN / WN);
  const int z = bz;
  const int m0 = by * BM;
  const int n0 = bx * BN;
  const unsigned char* Ab = A + (long)(z / aDiv) * aStr + (long)m0 * 1024;
  const unsigned char* Bb = BT + (long)(z % bMod) * bStr + (long)n0 * 1024;

  f32x4 acc[FM][FN] = {};
  constexpr int PA = (BM * 128) / (256 * 16);
  constexpr int PB = (BN * 128) / (256 * 16);

  for (int k0 = 0; k0 < 1024; k0 += 128) {
#pragma unroll
    for (int p = 0; p < PA; ++p) {
      int e = (p * 256 + t) * 16;
      int r = e >> 7, u = (e >> 4) & 7;
      int gcol = ((u ^ (r & 7)) << 4);
      gload_lds16(Ab + (long)r * 1024 + k0 + gcol, &At[e]);
    }
#pragma unroll
    for (int p = 0; p < PB; ++p) {
      int e = (p * 256 + t) * 16;
      int r = e >> 7, u = (e >> 4) & 7;
      int gcol = ((u ^ (r & 7)) << 4);
      gload_lds16(Bb + (long)r * 1024 + k0 + gcol, &Bt[e]);
    }
    __syncthreads();
#pragma unroll
    for (int kk = 0; kk < 128; kk += 32) {
      long af[FM], bf[FN];
#pragma unroll
      for (int m = 0; m < FM; ++m) {
        int row = wr + m * 16 + c;
        int un = (kk >> 4) + (g >> 1);
        af[m] = *(const long*)&At[row * 128 + ((un ^ (row & 7)) << 4) + (g & 1) * 8];
      }
#pragma unroll
      for (int n = 0; n < FN; ++n) {
        int row = wc + n * 16 + c;
        int un = (kk >> 4) + (g >> 1);
        bf[n] = *(const long*)&Bt[row * 128 + ((un ^ (row & 7)) << 4) + (g & 1) * 8];
      }
      __builtin_amdgcn_s_setprio(1);
#pragma unroll
      for (int m = 0; m < FM; ++m)
#pragma unroll
        for (int n = 0; n < FN; ++n)
          acc[m][n] = __builtin_amdgcn_mfma_f32_16x16x32_fp8_fp8(af[m], bf[n], acc[m][n], 0, 0, 0);
      __builtin_amdgcn_s_setprio(0);
    }
    __syncthreads();
  }

  const long cbase = (long)z * cStr;
#pragma unroll
  for (int m = 0; m < FM; ++m)
#pragma unroll
    for (int n = 0; n < FN; ++n) {
      int row0 = m0 + wr + m * 16 + g * 4;
      int col  = n0 + wc + n * 16 + c;
      unsigned p01 = cvt2fp8(acc[m][n][0] * scale, acc[m][n][1] * scale);
      unsigned p23 = cvt2fp8(acc[m][n][2] * scale, acc[m][n][3] * scale);
      if constexpr (TRANS == 0) {
        unsigned char* Cp = Cout + cbase + (long)row0 * ldc + col;
        Cp[0]            = (unsigned char)p01;
        Cp[(long)ldc]    = (unsigned char)(p01 >> 8);
        Cp[(long)ldc*2]  = (unsigned char)p23;
        Cp[(long)ldc*3]  = (unsigned char)(p23 >> 8);
      } else {
        unsigned word = (p01 & 0xFFFFu) | (p23 << 16);
        *(unsigned*)(Cout + cbase + (long)col * ldc + row0) = word;
      }
    }
}

// ---------------- flash attention (fp8, split-KV: 2 blocks per (q0,bh)) ----
// Round-18 fix of r17: keep split-KV (grid 1024 = 4 blocks/CU by LDS 40KB and
// VGPR<=128) but REVERT launch_bounds to (256,2).  r17's (256,4) made the
// allocator pick VGPR=64 -> 318 MB spills (same failure as r2/r11).  With
// (256,2) the compiler lands at ~112 VGPR (r15 evidence), and 112<=128
// already permits 4 waves/SIMD in HW — the bound need not (and must not)
// force it.  Body = r15-validated structure.
// LDS (40 KB): Qt[128][128]fp8 | Kt[128][128]fp8 | Vt8[64][128]fp8;
// Pl8 aliases Qt.  128B rows, 16B-unit XOR unit^(row&7).
__global__ __launch_bounds__(256, 2)
void flash_attn(const unsigned char* __restrict__ R, const unsigned char* __restrict__ X,
                const unsigned char* __restrict__ VT,
                float* __restrict__ Opart, float* __restrict__ ML)
{
  __shared__ __align__(16) unsigned char Sh[40960]; // 40 KB
  unsigned char* Qt  = Sh;             // [128][128] fp8 (queries = X rows)
  unsigned char* Kt  = Sh + 16384;     // [128][128] fp8 (keys = R rows)
  unsigned char* Vt8 = Sh + 32768;     // [64][128] fp8
  unsigned char* Pl8 = Sh;             // [128][128] fp8, aliases Qt

  unsigned fid = blockIdx.x + gridDim.x * blockIdx.y;
  unsigned nwg = gridDim.x * gridDim.y;          // 1024
  unsigned sid = xcd_swz(fid, nwg);
  const int q0    = (sid % gridDim.x) * 128;
  const int rest  = sid / gridDim.x;             // 0..127
  const int bh    = rest >> 1;
  const int split = rest & 1;

  const int t = threadIdx.x;
  const int l = t & 63;
  const int w = t >> 6;
  const int g = l >> 4;
  const int c = l & 15;
  const int b = bh >> 4;

  const unsigned char* Qq = X + (long)b * (1024 * 1024) + (long)q0 * 1024; // queries
  const unsigned char* Kb = R + (long)bh * (1024 * 1024);                  // keys
  const unsigned char* Vb = VT + (long)bh * (64 * 1024);

  f32x4 accO[2][4] = {};
  float mrun[2][4], lrun[2][4];
#pragma unroll
  for (int m = 0; m < 2; ++m)
#pragma unroll
    for (int r = 0; r < 4; ++r) { mrun[m][r] = -1e30f; lrun[m][r] = 0.f; }

  const float scale = 8.0f; // (1/32 score scale) * 256 (R prescale)

  const int mlo = split * 512, mhi = mlo + 512;
  for (int m0 = mlo; m0 < mhi; m0 += 128) {
    // ---- S = Q(128xK) * Keys(128xK)^T, K=1024 tiled by 128 (fp8)
    f32x4 accS[2][8] = {};
    for (int k0 = 0; k0 < 1024; k0 += 128) {
#pragma unroll
      for (int p = 0; p < 4; ++p) {
        int e = (p * 256 + t) * 16;
        int r = e >> 7, u = (e >> 4) & 7;
        int gcol = ((u ^ (r & 7)) << 4);
        gload_lds16(Qq + (long)r * 1024 + k0 + gcol, &Qt[e]);
      }
#pragma unroll
      for (int p = 0; p < 4; ++p) {
        int e = (p * 256 + t) * 16;
        int r = e >> 7, u = (e >> 4) & 7;
        int gcol = ((u ^ (r & 7)) << 4);
        gload_lds16(Kb + (long)(m0 + r) * 1024 + k0 + gcol, &Kt[e]);
      }
      __syncthreads();
#pragma unroll
      for (int kk = 0; kk < 128; kk += 32) {
        long af[2], bf[8];
#pragma unroll
        for (int m = 0; m < 2; ++m) {
          int row = w * 32 + m * 16 + c;
          int un = (kk >> 4) + (g >> 1);
          af[m] = *(const long*)&Qt[row * 128 + ((un ^ (row & 7)) << 4) + (g & 1) * 8];
        }
#pragma unroll
        for (int n = 0; n < 8; ++n) {
          int row = n * 16 + c;
          int un = (kk >> 4) + (g >> 1);
          bf[n] = *(const long*)&Kt[row * 128 + ((un ^ (row & 7)) << 4) + (g & 1) * 8];
        }
        __builtin_amdgcn_s_setprio(1);
#pragma unroll
        for (int m = 0; m < 2; ++m)
#pragma unroll
          for (int n = 0; n < 8; ++n)
            accS[m][n] = __builtin_amdgcn_mfma_f32_16x16x32_fp8_fp8(af[m], bf[n], accS[m][n], 0, 0, 0);
        __builtin_amdgcn_s_setprio(0);
      }
      __syncthreads();
    }
    // stage V slab [64][128] fp8 (flies under softmax; drained at syncthreads)
#pragma unroll
    for (int p = 0; p < 2; ++p) {
      int e = (p * 256 + t) * 16;
      int r = e >> 7, u = (e >> 4) & 7;
      int gcol = ((u ^ (r & 7)) << 4);
      gload_lds16(Vb + (long)r * 1024 + m0 + gcol, &Vt8[e]);
    }
    // ---- online softmax update (rows spread over 16-lane groups)
    float alpha[2][4];
#pragma unroll
    for (int m = 0; m < 2; ++m) {
#pragma unroll
      for (int r = 0; r < 4; ++r) {
        float mx = -1e30f;
#pragma unroll
        for (int n = 0; n < 8; ++n) mx = fmaxf(mx, accS[m][n][r]);
#pragma unroll
        for (int s = 1; s < 16; s <<= 1) mx = fmaxf(mx, __shfl_xor(mx, s));
        mx *= scale;
        float mnew = fmaxf(mrun[m][r], mx);
        float a = __expf(mrun[m][r] - mnew);
        alpha[m][r] = a;
        float sum = 0.f;
#pragma unroll
        for (int n = 0; n < 8; ++n) {
          float pe = __expf(accS[m][n][r] * scale - mnew);
          accS[m][n][r] = pe;
          sum += pe;
        }
#pragma unroll
        for (int s = 1; s < 16; s <<= 1) sum += __shfl_xor(sum, s);
        lrun[m][r] = lrun[m][r] * a + sum;
        mrun[m][r] = mnew;
      }
    }
    // P -> LDS (fp8, swizzled), aliases Qt (safe: last k0 barrier passed)
#pragma unroll
    for (int m = 0; m < 2; ++m)
#pragma unroll
      for (int n = 0; n < 8; ++n)
#pragma unroll
        for (int r = 0; r < 4; ++r) {
          int row = w * 32 + m * 16 + g * 4 + r;
          Pl8[row * 128 + ((n ^ (row & 7)) << 4) + c] =
              (unsigned char)cvt2fp8(accS[m][n][r], 0.f);
        }
    __syncthreads();   // Pl8 visible + Vt8 staged (vmcnt drained by barrier)
    // ---- O = O*alpha + P(32x128) @ V(128x64)   (fp8 MFMA)
#pragma unroll
    for (int m = 0; m < 2; ++m)
#pragma unroll
      for (int n = 0; n < 4; ++n)
#pragma unroll
        for (int r = 0; r < 4; ++r)
          accO[m][n][r] *= alpha[m][r];
#pragma unroll
    for (int kk = 0; kk < 128; kk += 32) {
      long pa[2], vb[4];
#pragma unroll
      for (int m = 0; m < 2; ++m) {
        int row = w * 32 + m * 16 + c;
        int un = (kk >> 4) + (g >> 1);
        pa[m] = *(const long*)&Pl8[row * 128 + ((un ^ (row & 7)) << 4) + (g & 1) * 8];
      }
#pragma unroll
      for (int n = 0; n < 4; ++n) {
        int row = n * 16 + c;
        int un = (kk >> 4) + (g >> 1);
        vb[n] = *(const long*)&Vt8[row * 128 + ((un ^ (row & 7)) << 4) + (g & 1) * 8];
      }
      __builtin_amdgcn_s_setprio(1);
#pragma unroll
      for (int m = 0; m < 2; ++m)
#pragma unroll
        for (int n = 0; n < 4; ++n)
          accO[m][n] = __builtin_amdgcn_mfma_f32_16x16x32_fp8_fp8(pa[m], vb[n], accO[m][n], 0, 0, 0);
      __builtin_amdgcn_s_setprio(0);
    }
    __syncthreads();   // all done reading Pl8/Vt8 before next m0 restage
  }
  // epilogue: write unnormalized O (f32) + per-row (m, l) partials
  const int part = (bh << 1) + split;
  float* Op = Opart + (long)part * 65536;        // [1024][64] f32
#pragma unroll
  for (int m = 0; m < 2; ++m)
#pragma unroll
    for (int n = 0; n < 4; ++n)
#pragma unroll
      for (int r = 0; r < 4; ++r) {
        int row = q0 + w * 32 + m * 16 + g * 4 + r;
        int col = n * 16 + c;
        Op[(long)row * 64 + col] = accO[m][n][r];
      }
  if (c == 0) {
#pragma unroll
    for (int m = 0; m < 2; ++m)
#pragma unroll
      for (int r = 0; r < 4; ++r) {
        int row = q0 + w * 32 + m * 16 + g * 4 + r;
        ML[(long)part * 2048 + row * 2]     = mrun[m][r];
        ML[(long)part * 2048 + row * 2 + 1] = lrun[m][r];
      }
  }
}

// ---------------- split-KV merge: combine 2 partials -> concat bf16 --------
// 1M threads, 4 v-elements each.  O = (O0*a0 + O1*a1) / (l0*a0 + l1*a1).
__global__ void flash_merge(const float* __restrict__ Opart, const float* __restrict__ ML,
                            unsigned short* __restrict__ Yc)
{
  int i = blockIdx.x * blockDim.x + threadIdx.x;  // 0 .. 1M
  int bh  = i >> 14;
  int rem = i & 16383;
  int row = rem >> 4;
  int v4  = (rem & 15) * 4;
  int p0 = bh << 1;
  float m0 = ML[(long)p0 * 2048 + row * 2];
  float l0 = ML[(long)p0 * 2048 + row * 2 + 1];
  float m1 = ML[(long)(p0 + 1) * 2048 + row * 2];
  float l1 = ML[(long)(p0 + 1) * 2048 + row * 2 + 1];
  float mn = fmaxf(m0, m1);
  float a0 = __expf(m0 - mn), a1 = __expf(m1 - mn);
  float inv = 1.f / (l0 * a0 + l1 * a1);
  f32x4 o0 = *(const f32x4*)&Opart[(long)p0 * 65536 + (long)row * 64 + v4];
  f32x4 o1 = *(const f32x4*)&Opart[(long)(p0 + 1) * 65536 + (long)row * 64 + v4];
  int b = bh >> 4, h = bh & 15;
  s16x4 o;
  o[0] = (short)f2bf((o0[0] * a0 + o1[0] * a1) * inv);
  o[1] = (short)f2bf((o0[1] * a0 + o1[1] * a1) * inv);
  o[2] = (short)f2bf((o0[2] * a0 + o1[2] * a1) * inv);
  o[3] = (short)f2bf((o0[3] * a0 + o1[3] * a1) * inv);
  *(s16x4*)(Yc + (long)b * (1024 * 1024) + (long)row * 1024 + h * 64 + v4) = o;
}

// ---------------- launch ----------------
extern "C" void kernel_launch(void* const* d_in, const int* in_sizes, int n_in,
                              void* d_out, int out_size, void* d_ws, size_t ws_size,
                              hipStream_t stream) {
  (void)in_sizes; (void)n_in; (void)out_size; (void)ws_size;
  const float* X  = (const float*)d_in[0];
  const float* Wq = (const float*)d_in[1];
  const float* Wk = (const float*)d_in[2];
  const float* Wv = (const float*)d_in[3];
  const float* Wo = (const float*)d_in[4];
  float* Y = (float*)d_out;
  char* ws = (char*)d_ws;

  const long MB = 1L << 20;
  unsigned char*  Xf8   = (unsigned char*)(ws + 0);         // 4 MB
  unsigned char*  Wqf8  = (unsigned char*)(ws + 4  * MB);   // 16 MB
  unsigned char*  Wkf8  = (unsigned char*)(ws + 20 * MB);   // 16 MB
  unsigned char*  Mf8   = (unsigned char*)(ws + 36 * MB);   // 16 MB  (M = Wq·Wk^T, /256)
  unsigned char*  WvTf8 = (unsigned char*)(ws + 52 * MB);   // 1 MB
  unsigned char*  VTb8  = (unsigned char*)(ws + 56 * MB);   // 4 MB
  unsigned short* Ccat  = (unsigned short*)(ws + 60 * MB);  // 8 MB
  unsigned short* WoT   = (unsigned short*)(ws + 68 * MB);  // 2 MB
  unsigned char*  Rf8   = (unsigned char*)(ws + 72 * MB);   // 64 MB
  float*          Opart = (float*)(ws + 136 * MB);          // 32 MB
  float*          MLb   = (float*)(ws + 168 * MB);          // 1 MB -> 169 MB peak

  const long M1 = 1L << 20; // byte stride for [1024][1024] fp8

  // converts (all inputs -> fp8; Wo -> bf16 transposed)
  conv_fp8<<<2048, 256, 0, stream>>>(X,  Xf8,  524288);
  conv_fp8<<<8192, 256, 0, stream>>>(Wq, Wqf8, 2097152);
  conv_fp8<<<8192, 256, 0, stream>>>(Wk, Wkf8, 2097152);
  convT_wv_f8<<<4096, 256, 0, stream>>>(Wv, WvTf8);

  // Mf8[h] = (Wq[h] @ Wk[h]^T)/256 in e4m3   (bt-form: A=Wq, BT=Wk)
  gemm_f8<128, 128, 2, 2, 0><<<dim3(8, 8, 16), 256, 0, stream>>>(
      Wqf8, Wkf8, Mf8, 1, M1, 16, M1, M1, 1024, 0.00390625f);

  // Rf8[b,h] = X[b] @ (M[h]^T/256) in e4m3   (bt-form: A=X, BT=Mf8)
  gemm_f8<128, 128, 2, 2, 0><<<dim3(8, 8, 64), 256, 0, stream>>>(
      Xf8, Mf8, Rf8, 16, M1, 16, M1, M1, 1024, 1.0f);

  // VTb8[b,h][64][1024] = (X[b] @ Wv[h]) transposed, e4m3
  gemm_f8<128, 64, 4, 1, 1><<<dim3(1, 8, 64), 256, 0, stream>>>(
      Xf8, WvTf8, VTb8, 16, M1, 16, 65536, 65536, 1024, 1.0f);

  // flash attention, split-KV (2 partials per (q0,bh)) + merge -> concat bf16
  flash_attn<<<dim3(8, 128), 256, 0, stream>>>(Rf8, Xf8, VTb8, Opart, MLb);
  flash_merge<<<4096, 256, 0, stream>>>(Opart, MLb, Ccat);

  // Y = concat @ Wo, masked epilogue (col > row -> -1e9), fp32 out;
  // fully-masked tiles (n0 > m0+127) skip their K-loop.
  convT_wo<<<4096, 256, 0, stream>>>(Wo, WoT);
  gemm_bt<128, 128, 2, 2, 2><<<dim3(8, 8, 4), 256, 0, stream>>>(
      Ccat, WoT, Y, 1, M1, 1, 0, M1, 1024);
}

// Round 19
// 335.748 us; speedup vs baseline: 1.2054x; 1.0363x over previous
//
#include <hip/hip_runtime.h>
#include <stdint.h>

typedef short s16x8 __attribute__((ext_vector_type(8)));
typedef float f32x4 __attribute__((ext_vector_type(4)));

__device__ __forceinline__ unsigned short f2bf(float f) {
  union { float f; unsigned int u; } v; v.f = f;
  unsigned int r = v.u + 0x7FFFu + ((v.u >> 16) & 1u);
  return (unsigned short)(r >> 16);
}

// HW packed f32x2 -> e4m3x2 (low word: byte0=cvt(a), byte1=cvt(b))
__device__ __forceinline__ unsigned cvt2fp8(float a, float b) {
#if __has_builtin(__builtin_amdgcn_cvt_pk_fp8_f32)
  return (unsigned)__builtin_amdgcn_cvt_pk_fp8_f32(a, b, 0, false);
#else
  unsigned r;
  asm("v_cvt_pk_fp8_f32 %0, %1, %2" : "=v"(r) : "v"(a), "v"(b));
  return r;
#endif
}

__device__ __forceinline__ void gload_lds16(const void* g, void* l) {
  __builtin_amdgcn_global_load_lds(
      (const __attribute__((address_space(1))) unsigned int*)g,
      (__attribute__((address_space(3))) unsigned int*)l, 16, 0, 0);
}

// T1 XCD-aware bijective block swizzle (grid size must be %8==0; all ours are).
__device__ __forceinline__ unsigned xcd_swz(unsigned fid, unsigned nwg) {
  unsigned cpx = nwg >> 3;
  return (fid & 7) * cpx + (fid >> 3);
}

// ---------------- converts ----------------
// f32 -> fp8 e4m3 via HW cvt (values ~N(0,1) or bounded << 448)
__global__ void conv_fp8(const float* __restrict__ in, unsigned char* __restrict__ out, int n8) {
  int i = blockIdx.x * blockDim.x + threadIdx.x;
  if (i >= n8) return;
  const f32x4* p = (const f32x4*)(in + (long)i * 8);
  f32x4 a = p[0], b = p[1];
  unsigned long w = (unsigned long)(cvt2fp8(a[0], a[1]) & 0xFFFFu)
                  | ((unsigned long)(cvt2fp8(a[2], a[3]) & 0xFFFFu) << 16)
                  | ((unsigned long)(cvt2fp8(b[0], b[1]) & 0xFFFFu) << 32)
                  | ((unsigned long)(cvt2fp8(b[2], b[3]) & 0xFFFFu) << 48);
  *(unsigned long*)(out + (long)i * 8) = w;
}

// two arrays in one launch (Wq, Wk): blocks [0,half) -> 0, [half,2*half) -> 1
__global__ void conv_fp8_2(const float* __restrict__ in0, unsigned char* __restrict__ out0,
                           const float* __restrict__ in1, unsigned char* __restrict__ out1,
                           int n8each) {
  int half = gridDim.x >> 1;
  int which = blockIdx.x >= half;
  int i = (blockIdx.x - which * half) * blockDim.x + threadIdx.x;
  if (i >= n8each) return;
  const float* in = which ? in1 : in0;
  unsigned char* out = which ? out1 : out0;
  const f32x4* p = (const f32x4*)(in + (long)i * 8);
  f32x4 a = p[0], b = p[1];
  unsigned long w = (unsigned long)(cvt2fp8(a[0], a[1]) & 0xFFFFu)
                  | ((unsigned long)(cvt2fp8(a[2], a[3]) & 0xFFFFu) << 16)
                  | ((unsigned long)(cvt2fp8(b[0], b[1]) & 0xFFFFu) << 32)
                  | ((unsigned long)(cvt2fp8(b[2], b[3]) & 0xFFFFu) << 48);
  *(unsigned long*)(out + (long)i * 8) = w;
}

// Wv: [16][1024][64] f32 -> WvT [16][64][1024] fp8
__global__ void convT_wv_f8(const float* __restrict__ in, unsigned char* __restrict__ out) {
  int i = blockIdx.x * blockDim.x + threadIdx.x; // 1M
  int v = i & 63, d = (i >> 6) & 1023, h = i >> 16;
  out[((long)h * 64 + v) * 1024 + d] = (unsigned char)cvt2fp8(in[i], 0.f);
}

// Wo: [1024][1024] f32 [c][e] -> WoT [e][c] bf16
__global__ void convT_wo(const float* __restrict__ in, unsigned short* __restrict__ out) {
  int i = blockIdx.x * blockDim.x + threadIdx.x; // 1M
  int e = i & 1023, c = i >> 10;
  out[(long)e * 1024 + c] = f2bf(in[i]);
}

// ---------------- bf16 bt-GEMM (Y only), K=1024 fixed ----------------
// CMODE 2: f32 masked (col>row -> -1e9); fully-masked tiles skip the K-loop.
template<int BM, int BN, int WAVES_M, int WAVES_N, int CMODE>
__global__ __launch_bounds__(256, 2)
void gemm_bt(const unsigned short* __restrict__ A, const unsigned short* __restrict__ BT,
             void* __restrict__ Cout, int aDiv, long aStr, int bMod, long bStr,
             long cStr, int ldc)
{
  constexpr int BK = 64;
  constexpr int FM = BM / (WAVES_M * 16);
  constexpr int FN = BN / (WAVES_N * 16);
  __shared__ __align__(16) unsigned short At[BM * BK];
  __shared__ __align__(16) unsigned short Bt[BN * BK];

  unsigned fid = blockIdx.x + gridDim.x * (blockIdx.y + gridDim.y * blockIdx.z);
  unsigned nwg = gridDim.x * gridDim.y * gridDim.z;
  unsigned sid = xcd_swz(fid, nwg);
  unsigned bx = sid % gridDim.x;
  unsigned rem = sid / gridDim.x;
  unsigned by = rem % gridDim.y;
  unsigned bz = rem / gridDim.y;

  const int t = threadIdx.x;
  const int l = t & 63;
  const int g = l >> 4, c = l & 15;
  const int w = t >> 6;
  const int wr = (w / WAVES_N) * (BM / WAVES_M);
  const int wc = (w % WAVES_N) * (BN / WAVES_N);
  const int z = bz;
  const int m0 = by * BM;
  const int n0 = bx * BN;
  const unsigned short* Ab = A + (long)(z / aDiv) * aStr + (long)m0 * 1024;
  const unsigned short* Bb = BT + (long)(z % bMod) * bStr + (long)n0 * 1024;

  const long cbase = (long)z * cStr;

  if constexpr (CMODE == 2) {
    if (n0 > m0 + BM - 1) {
#pragma unroll
      for (int m = 0; m < FM; ++m)
#pragma unroll
        for (int n = 0; n < FN; ++n)
#pragma unroll
          for (int r = 0; r < 4; ++r) {
            int row = wr + m * 16 + g * 4 + r;
            int col = n0 + wc + n * 16 + c;
            ((float*)Cout)[cbase + (long)(m0 + row) * ldc + col] = -1e9f;
          }
      return;
    }
  }

  f32x4 acc[FM][FN] = {};
  constexpr int PA = (BM * BK) / 2048;
  constexpr int PB = (BN * BK) / 2048;

  for (int k0 = 0; k0 < 1024; k0 += BK) {
#pragma unroll
    for (int p = 0; p < PA; ++p) {
      int e = (p * 256 + t) * 8;
      int row = e >> 6, col = e & 63;
      gload_lds16(Ab + (long)row * 1024 + k0 + col, &At[e]);
    }
#pragma unroll
    for (int p = 0; p < PB; ++p) {
      int e = (p * 256 + t) * 8;
      int row = e >> 6, col = e & 63;
      gload_lds16(Bb + (long)row * 1024 + k0 + col, &Bt[e]);
    }
    __syncthreads();
#pragma unroll
    for (int kk = 0; kk < BK; kk += 32) {
      s16x8 af[FM], bf[FN];
#pragma unroll
      for (int m = 0; m < FM; ++m)
        af[m] = *(const s16x8*)&At[(wr + m * 16 + c) * BK + kk + g * 8];
#pragma unroll
      for (int n = 0; n < FN; ++n)
        bf[n] = *(const s16x8*)&Bt[(wc + n * 16 + c) * BK + kk + g * 8];
#pragma unroll
      for (int m = 0; m < FM; ++m)
#pragma unroll
        for (int n = 0; n < FN; ++n)
          acc[m][n] = __builtin_amdgcn_mfma_f32_16x16x32_bf16(af[m], bf[n], acc[m][n], 0, 0, 0);
    }
    __syncthreads();
  }

#pragma unroll
  for (int m = 0; m < FM; ++m)
#pragma unroll
    for (int n = 0; n < FN; ++n)
#pragma unroll
      for (int r = 0; r < 4; ++r) {
        int row = wr + m * 16 + g * 4 + r;
        int col = n0 + wc + n * 16 + c;
        int grow = m0 + row;
        float v = acc[m][n][r];
        if constexpr (CMODE == 0) {
          ((unsigned short*)Cout)[cbase + (long)grow * ldc + col] = f2bf(v);
        } else if constexpr (CMODE == 2) {
          ((float*)Cout)[cbase + (long)grow * ldc + col] = (col > grow) ? -1e9f : v;
        }
      }
}

// ---------------- generalized fp8 bt-GEMM (BK=128, r12-validated structure) -
// C[i][j] = scale * sum_k A[i][k]*BT[j][k]; A,BT e4m3 with 1024B rows.
// TRANS 0: fp8 out at [row*ldc+col]; TRANS 1: fp8 out transposed (u32 packs).
// cStr/aStr/bStr/ldc in BYTES.  128B LDS rows + 16B-unit XOR unit^(row&7);
// staged tiles keep LDS linear + inverse-swizzled GLOBAL source (rule #21).
// [r16: MX K=128 spills at this fan-out; r13: counted-vmcnt dbuf regresses.]
template<int BM, int BN, int WM, int WN, int TRANS>
__global__ __launch_bounds__(256, 2)
void gemm_f8(const unsigned char* __restrict__ A, const unsigned char* __restrict__ BT,
             unsigned char* __restrict__ Cout, int aDiv, long aStr, int bMod, long bStr,
             long cStr, int ldc, float scale)
{
  constexpr int FM = BM / (WM * 16);
  constexpr int FN = BN / (WN * 16);
  __shared__ __align__(16) unsigned char At[BM * 128];
  __shared__ __align__(16) unsigned char Bt[BN * 128];

  unsigned fid = blockIdx.x + gridDim.x * (blockIdx.y + gridDim.y * blockIdx.z);
  unsigned nwg = gridDim.x * gridDim.y * gridDim.z;
  unsigned sid = xcd_swz(fid, nwg);
  unsigned bx = sid % gridDim.x;
  unsigned rem = sid / gridDim.x;
  unsigned by = rem % gridDim.y;
  unsigned bz = rem / gridDim.y;

  const int t = threadIdx.x;
  const int l = t & 63;
  const int g = l >> 4, c = l & 15;
  const int w = t >> 6;
  const int wr = (w / WN) * (BM / WM);
  const int wc = (w % WN) * (BN / WN);
  const int z = bz;
  const int m0 = by * BM;
  const int n0 = bx * BN;
  const unsigned char* Ab = A + (long)(z / aDiv) * aStr + (long)m0 * 1024;
  const unsigned char* Bb = BT + (long)(z % bMod) * bStr + (long)n0 * 1024;

  f32x4 acc[FM][FN] = {};
  constexpr int PA = (BM * 128) / (256 * 16);
  constexpr int PB = (BN * 128) / (256 * 16);

  for (int k0 = 0; k0 < 1024; k0 += 128) {
#pragma unroll
    for (int p = 0; p < PA; ++p) {
      int e = (p * 256 + t) * 16;
      int r = e >> 7, u = (e >> 4) & 7;
      int gcol = ((u ^ (r & 7)) << 4);
      gload_lds16(Ab + (long)r * 1024 + k0 + gcol, &At[e]);
    }
#pragma unroll
    for (int p = 0; p < PB; ++p) {
      int e = (p * 256 + t) * 16;
      int r = e >> 7, u = (e >> 4) & 7;
      int gcol = ((u ^ (r & 7)) << 4);
      gload_lds16(Bb + (long)r * 1024 + k0 + gcol, &Bt[e]);
    }
    __syncthreads();
#pragma unroll
    for (int kk = 0; kk < 128; kk += 32) {
      long af[FM], bf[FN];
#pragma unroll
      for (int m = 0; m < FM; ++m) {
        int row = wr + m * 16 + c;
        int un = (kk >> 4) + (g >> 1);
        af[m] = *(const long*)&At[row * 128 + ((un ^ (row & 7)) << 4) + (g & 1) * 8];
      }
#pragma unroll
      for (int n = 0; n < FN; ++n) {
        int row = wc + n * 16 + c;
        int un = (kk >> 4) + (g >> 1);
        bf[n] = *(const long*)&Bt[row * 128 + ((un ^ (row & 7)) << 4) + (g & 1) * 8];
      }
      __builtin_amdgcn_s_setprio(1);
#pragma unroll
      for (int m = 0; m < FM; ++m)
#pragma unroll
        for (int n = 0; n < FN; ++n)
          acc[m][n] = __builtin_amdgcn_mfma_f32_16x16x32_fp8_fp8(af[m], bf[n], acc[m][n], 0, 0, 0);
      __builtin_amdgcn_s_setprio(0);
    }
    __syncthreads();
  }

  const long cbase = (long)z * cStr;
#pragma unroll
  for (int m = 0; m < FM; ++m)
#pragma unroll
    for (int n = 0; n < FN; ++n) {
      int row0 = m0 + wr + m * 16 + g * 4;
      int col  = n0 + wc + n * 16 + c;
      unsigned p01 = cvt2fp8(acc[m][n][0] * scale, acc[m][n][1] * scale);
      unsigned p23 = cvt2fp8(acc[m][n][2] * scale, acc[m][n][3] * scale);
      if constexpr (TRANS == 0) {
        unsigned char* Cp = Cout + cbase + (long)row0 * ldc + col;
        Cp[0]            = (unsigned char)p01;
        Cp[(long)ldc]    = (unsigned char)(p01 >> 8);
        Cp[(long)ldc*2]  = (unsigned char)p23;
        Cp[(long)ldc*3]  = (unsigned char)(p23 >> 8);
      } else {
        unsigned word = (p01 & 0xFFFFu) | (p23 << 16);
        *(unsigned*)(Cout + cbase + (long)col * ldc + row0) = word;
      }
    }
}

// ---------------- flash attention (fp8, operand-swapped for L2 locality) ---
// S[q][k] = sum_d X[q][d]·R[k][d], R[b,h] = (X[b]·M^T[h])/256 (M = Wq·Wk^T).
// Queries from X[b] (1 MB, L2-hot across all 128 wgs of batch b); keys from
// R[b,h], each wg reads its slice once (FETCH ~39 MB total).  r15-validated.
// LDS (40 KB): Qt[128][128]fp8 | Kt[128][128]fp8 | Vt8[64][128]fp8;
// Pl8[128][128]fp8 aliases Qt.  128B rows, 16B-unit XOR unit^(row&7);
// staged tiles keep LDS linear + inverse-swizzled GLOBAL source (rule #21).
// Softmax scale = 8 (1/32 score * 256 R-prescale).
// Structural ceiling note (r16-r18): per-wave acc (~96 regs) + 112 VGPR caps
// residency at 2 blocks/CU regardless of grid/LDS (r17 (256,4) -> VGPR=64 +
// 318MB spills; r18 split-KV at (256,2) -> occupancy unchanged).  2-phase
// stage->drain->MFMA is the binding structure; coarse pipelining nulls
// (r5, r13).  Keep bounds(256,2), 4 waves, QBLK=128, single-buffered k0.
__global__ __launch_bounds__(256, 2)
void flash_attn(const unsigned char* __restrict__ R, const unsigned char* __restrict__ X,
                const unsigned char* __restrict__ VT, unsigned short* __restrict__ Yc)
{
  __shared__ __align__(16) unsigned char Sh[40960]; // 40 KB
  unsigned char* Qt  = Sh;             // [128][128] fp8 (queries = X rows)
  unsigned char* Kt  = Sh + 16384;     // [128][128] fp8 (keys = R rows)
  unsigned char* Vt8 = Sh + 32768;     // [64][128] fp8
  unsigned char* Pl8 = Sh;             // [128][128] fp8, aliases Qt

  unsigned fid = blockIdx.x + gridDim.x * blockIdx.y;
  unsigned nwg = gridDim.x * gridDim.y;
  unsigned sid = xcd_swz(fid, nwg);
  const int q0 = (sid % gridDim.x) * 128;
  const int bh = sid / gridDim.x;

  const int t = threadIdx.x;
  const int l = t & 63;
  const int w = t >> 6;
  const int g = l >> 4;
  const int c = l & 15;
  const int b = bh >> 4;

  const unsigned char* Qq = X + (long)b * (1024 * 1024) + (long)q0 * 1024; // queries
  const unsigned char* Kb = R + (long)bh * (1024 * 1024);                  // keys
  const unsigned char* Vb = VT + (long)bh * (64 * 1024);

  f32x4 accO[2][4] = {};
  float mrun[2][4], lrun[2][4];
#pragma unroll
  for (int m = 0; m < 2; ++m)
#pragma unroll
    for (int r = 0; r < 4; ++r) { mrun[m][r] = -1e30f; lrun[m][r] = 0.f; }

  const float scale = 8.0f; // (1/32 score scale) * 256 (R prescale)

  for (int m0 = 0; m0 < 1024; m0 += 128) {
    // ---- S = Q(128xK) * Keys(128xK)^T, K=1024 tiled by 128 (fp8)
    f32x4 accS[2][8] = {};
    for (int k0 = 0; k0 < 1024; k0 += 128) {
#pragma unroll
      for (int p = 0; p < 4; ++p) {
        int e = (p * 256 + t) * 16;
        int r = e >> 7, u = (e >> 4) & 7;
        int gcol = ((u ^ (r & 7)) << 4);
        gload_lds16(Qq + (long)r * 1024 + k0 + gcol, &Qt[e]);
      }
#pragma unroll
      for (int p = 0; p < 4; ++p) {
        int e = (p * 256 + t) * 16;
        int r = e >> 7, u = (e >> 4) & 7;
        int gcol = ((u ^ (r & 7)) << 4);
        gload_lds16(Kb + (long)(m0 + r) * 1024 + k0 + gcol, &Kt[e]);
      }
      __syncthreads();
#pragma unroll
      for (int kk = 0; kk < 128; kk += 32) {
        long af[2], bf[8];
#pragma unroll
        for (int m = 0; m < 2; ++m) {
          int row = w * 32 + m * 16 + c;
          int un = (kk >> 4) + (g >> 1);
          af[m] = *(const long*)&Qt[row * 128 + ((un ^ (row & 7)) << 4) + (g & 1) * 8];
        }
#pragma unroll
        for (int n = 0; n < 8; ++n) {
          int row = n * 16 + c;
          int un = (kk >> 4) + (g >> 1);
          bf[n] = *(const long*)&Kt[row * 128 + ((un ^ (row & 7)) << 4) + (g & 1) * 8];
        }
        __builtin_amdgcn_s_setprio(1);
#pragma unroll
        for (int m = 0; m < 2; ++m)
#pragma unroll
          for (int n = 0; n < 8; ++n)
            accS[m][n] = __builtin_amdgcn_mfma_f32_16x16x32_fp8_fp8(af[m], bf[n], accS[m][n], 0, 0, 0);
        __builtin_amdgcn_s_setprio(0);
      }
      __syncthreads();
    }
    // stage V slab [64][128] fp8 (flies under softmax; drained at syncthreads)
#pragma unroll
    for (int p = 0; p < 2; ++p) {
      int e = (p * 256 + t) * 16;
      int r = e >> 7, u = (e >> 4) & 7;
      int gcol = ((u ^ (r & 7)) << 4);
      gload_lds16(Vb + (long)r * 1024 + m0 + gcol, &Vt8[e]);
    }
    // ---- online softmax update (rows spread over 16-lane groups)
    float alpha[2][4];
#pragma unroll
    for (int m = 0; m < 2; ++m) {
#pragma unroll
      for (int r = 0; r < 4; ++r) {
        float mx = -1e30f;
#pragma unroll
        for (int n = 0; n < 8; ++n) mx = fmaxf(mx, accS[m][n][r]);
#pragma unroll
        for (int s = 1; s < 16; s <<= 1) mx = fmaxf(mx, __shfl_xor(mx, s));
        mx *= scale;
        float mnew = fmaxf(mrun[m][r], mx);
        float a = __expf(mrun[m][r] - mnew);
        alpha[m][r] = a;
        float sum = 0.f;
#pragma unroll
        for (int n = 0; n < 8; ++n) {
          float pe = __expf(accS[m][n][r] * scale - mnew);
          accS[m][n][r] = pe;
          sum += pe;
        }
#pragma unroll
        for (int s = 1; s < 16; s <<= 1) sum += __shfl_xor(sum, s);
        lrun[m][r] = lrun[m][r] * a + sum;
        mrun[m][r] = mnew;
      }
    }
    // P -> LDS (fp8, swizzled), aliases Qt (safe: last k0 barrier passed)
#pragma unroll
    for (int m = 0; m < 2; ++m)
#pragma unroll
      for (int n = 0; n < 8; ++n)
#pragma unroll
        for (int r = 0; r < 4; ++r) {
          int row = w * 32 + m * 16 + g * 4 + r;
          Pl8[row * 128 + ((n ^ (row & 7)) << 4) + c] =
              (unsigned char)cvt2fp8(accS[m][n][r], 0.f);
        }
    __syncthreads();   // Pl8 visible + Vt8 staged (vmcnt drained by barrier)
    // ---- O = O*alpha + P(32x128) @ V(128x64)   (fp8 MFMA)
#pragma unroll
    for (int m = 0; m < 2; ++m)
#pragma unroll
      for (int n = 0; n < 4; ++n)
#pragma unroll
        for (int r = 0; r < 4; ++r)
          accO[m][n][r] *= alpha[m][r];
#pragma unroll
    for (int kk = 0; kk < 128; kk += 32) {
      long pa[2], vb[4];
#pragma unroll
      for (int m = 0; m < 2; ++m) {
        int row = w * 32 + m * 16 + c;
        int un = (kk >> 4) + (g >> 1);
        pa[m] = *(const long*)&Pl8[row * 128 + ((un ^ (row & 7)) << 4) + (g & 1) * 8];
      }
#pragma unroll
      for (int n = 0; n < 4; ++n) {
        int row = n * 16 + c;
        int un = (kk >> 4) + (g >> 1);
        vb[n] = *(const long*)&Vt8[row * 128 + ((un ^ (row & 7)) << 4) + (g & 1) * 8];
      }
      __builtin_amdgcn_s_setprio(1);
#pragma unroll
      for (int m = 0; m < 2; ++m)
#pragma unroll
        for (int n = 0; n < 4; ++n)
          accO[m][n] = __builtin_amdgcn_mfma_f32_16x16x32_fp8_fp8(pa[m], vb[n], accO[m][n], 0, 0, 0);
      __builtin_amdgcn_s_setprio(0);
    }
    __syncthreads();   // all done reading Pl8/Vt8 before next m0 restage
  }
  // epilogue: divide by row-sum, write concat
  unsigned short* out = Yc + (long)b * (1024 * 1024) + (long)(bh & 15) * 64;
#pragma unroll
  for (int m = 0; m < 2; ++m)
#pragma unroll
    for (int n = 0; n < 4; ++n)
#pragma unroll
      for (int r = 0; r < 4; ++r) {
        int row = q0 + w * 32 + m * 16 + g * 4 + r;
        int col = n * 16 + c;
        out[(long)row * 1024 + col] = f2bf(accO[m][n][r] / lrun[m][r]);
      }
}

// ---------------- launch ----------------
extern "C" void kernel_launch(void* const* d_in, const int* in_sizes, int n_in,
                              void* d_out, int out_size, void* d_ws, size_t ws_size,
                              hipStream_t stream) {
  (void)in_sizes; (void)n_in; (void)out_size; (void)ws_size;
  const float* X  = (const float*)d_in[0];
  const float* Wq = (const float*)d_in[1];
  const float* Wk = (const float*)d_in[2];
  const float* Wv = (const float*)d_in[3];
  const float* Wo = (const float*)d_in[4];
  float* Y = (float*)d_out;
  char* ws = (char*)d_ws;

  const long MB = 1L << 20;
  unsigned char*  Xf8   = (unsigned char*)(ws + 0);         // 4 MB
  unsigned char*  Wqf8  = (unsigned char*)(ws + 4  * MB);   // 16 MB
  unsigned char*  Wkf8  = (unsigned char*)(ws + 20 * MB);   // 16 MB
  unsigned char*  Mf8   = (unsigned char*)(ws + 36 * MB);   // 16 MB  (M = Wq·Wk^T, /256)
  unsigned char*  WvTf8 = (unsigned char*)(ws + 52 * MB);   // 1 MB
  unsigned char*  VTb8  = (unsigned char*)(ws + 56 * MB);   // 4 MB
  unsigned short* Ccat  = (unsigned short*)(ws + 60 * MB);  // 8 MB
  unsigned short* WoT   = (unsigned short*)(ws + 68 * MB);  // 2 MB
  unsigned char*  Rf8   = (unsigned char*)(ws + 72 * MB);   // 64 MB -> 136 MB peak

  const long M1 = 1L << 20; // byte stride for [1024][1024] fp8

  // converts (all inputs -> fp8; Wo -> bf16 transposed)
  conv_fp8<<<2048, 256, 0, stream>>>(X,  Xf8,  524288);
  conv_fp8_2<<<16384, 256, 0, stream>>>(Wq, Wqf8, Wk, Wkf8, 2097152);
  convT_wv_f8<<<4096, 256, 0, stream>>>(Wv, WvTf8);

  // Mf8[h] = (Wq[h] @ Wk[h]^T)/256 in e4m3   (bt-form: A=Wq, BT=Wk)
  gemm_f8<128, 128, 2, 2, 0><<<dim3(8, 8, 16), 256, 0, stream>>>(
      Wqf8, Wkf8, Mf8, 1, M1, 16, M1, M1, 1024, 0.00390625f);

  // Rf8[b,h] = X[b] @ (M[h]^T/256) in e4m3   (bt-form: A=X, BT=Mf8)
  gemm_f8<128, 128, 2, 2, 0><<<dim3(8, 8, 64), 256, 0, stream>>>(
      Xf8, Mf8, Rf8, 16, M1, 16, M1, M1, 1024, 1.0f);

  // VTb8[b,h][64][1024] = (X[b] @ Wv[h]) transposed, e4m3
  gemm_f8<128, 64, 4, 1, 1><<<dim3(1, 8, 64), 256, 0, stream>>>(
      Xf8, WvTf8, VTb8, 16, M1, 16, 65536, 65536, 1024, 1.0f);

  // flash attention (queries from Xf8, keys from Rf8) -> concat bf16
  flash_attn<<<dim3(8, 64), 256, 0, stream>>>(Rf8, Xf8, VTb8, Ccat);

  // Y = concat @ Wo, masked epilogue (col > row -> -1e9), fp32 out;
  // fully-masked tiles (n0 > m0+127) skip their K-loop.
  convT_wo<<<4096, 256, 0, stream>>>(Wo, WoT);
  gemm_bt<128, 128, 2, 2, 2><<<dim3(8, 8, 4), 256, 0, stream>>>(
      Ccat, WoT, Y, 1, M1, 1, 0, M1, 1024);
}